// Round 5
// baseline (953.084 us; speedup 1.0000x reference)
//
#include <hip/hip_runtime.h>
#include <cstdint>
#include <cstddef>

#define Bn 128
#define Ln 1024
#define Fn 128
#define Hn 64
#define NGn 256           // 4*H
#define NCn 16
#define IN_DIM (Hn + Fn*Hn)   // 8256

typedef float    f32x2 __attribute__((ext_vector_type(2)));
typedef _Float16 f16x8 __attribute__((ext_vector_type(8)));

struct SlabR { f16x8 w[8]; f32x2 wb; };   // 32 + 2 VGPRs

__device__ __forceinline__ float fsigm(float x) {
    return __fdividef(1.0f, 1.0f + __expf(-x));
}
__device__ __forceinline__ float ftanh(float x) {
    float e = __expf(2.0f * x);
    return 1.0f - __fdividef(2.0f, e + 1.0f);
}
__device__ __forceinline__ float sigm_slow(float x) { return 1.0f / (1.0f + expf(-x)); }

template<int K>
__device__ __forceinline__ float quad_bcast(float v) {
    int i = __builtin_amdgcn_mov_dpp(__float_as_int(v), K * 0x55, 0xf, 0xf, true);
    return __int_as_float(i);
}

// gate-row owned by thread tid: g(tid) = (tid&3)*64 + (tid>>6)*16 + ((tid>>2)&15)
// Gw [((f*8 + i)*256 + tid)*8 + e] = (f16) W_gates[f][g(tid)][1 + 8i + e]   (coalesced 16B/lane)
// Gwb[f*256 + tid] = (W_gates[f][g(tid)][0], b_gates[f][g(tid)])
__global__ __launch_bounds__(256)
void prep_f16(const float* __restrict__ Wg, const float* __restrict__ bg,
              _Float16* __restrict__ Gw, f32x2* __restrict__ Gwb)
{
    const int f = blockIdx.x, tid = threadIdx.x;
    const int g = (tid & 3) * 64 + (tid >> 6) * 16 + ((tid >> 2) & 15);
    const float* src = Wg + ((size_t)f * NGn + g) * 65;
    f32x2 wb; wb[0] = src[0]; wb[1] = bg[f * NGn + g];
    Gwb[f * NGn + tid] = wb;
#pragma unroll
    for (int i = 0; i < 8; ++i) {
        f16x8 v;
#pragma unroll
        for (int e = 0; e < 8; ++e) v[e] = (_Float16)src[1 + 8*i + e];
        *(f16x8*)(Gw + (((size_t)f * 8 + i) * NGn + tid) * 8) = v;
    }
}

// Issue one step's per-thread W row (9 pinned loads) into register slab SL.
#define ISSUE_R(SL, MN)                                                         \
    do {                                                                        \
        const uint32_t vo_ = ((uint32_t)(MN) << 15) + ((uint32_t)tid << 4);     \
        _Pragma("unroll")                                                       \
        for (int i_ = 0; i_ < 8; ++i_)                                          \
            asm volatile("global_load_dwordx4 %0, %1, %2"                       \
                         : "=v"(SL.w[i_])                                       \
                         : "v"(vo_ + (uint32_t)(i_ * 4096)), "s"(Gw));          \
        asm volatile("global_load_dwordx2 %0, %1, %2"                           \
                     : "=v"(SL.wb)                                              \
                     : "v"(((uint32_t)(MN) << 11) + ((uint32_t)tid << 3)),      \
                       "s"(Gwb));                                               \
    } while (0)

// One step consuming register slab CUR; issues step J+2's slab into FREE.
// vmcnt(18): the two newer slabs (9 loads each) stay in flight, CUR certified.
#define STEPR(J, CUR, FREE)                                                     \
    {                                                                           \
        const int   j_   = (J);                                                 \
        const int   mj_  = m_lds[j_];                                           \
        const float xj_  = x_lds[j_];                                           \
        const float dj_  = d_lds[j_];                                           \
        const int   pfi_ = (j_ + 2 < len) ? (j_ + 2) : (len - 1);               \
        const int   mn_  = m_lds[pfi_];                                         \
        const float wdv_ = wd_lds[mj_], bdv_ = bd_lds[mj_];                     \
        const float vh_  = h_lds[(mj_ << 6) + l];                               \
        ISSUE_R(FREE, mn_);                                                     \
        const float dec_ = __expf(-fmaxf(0.0f, fmaf(wdv_, dj_, bdv_)));         \
        asm volatile("s_waitcnt vmcnt(18)" ::: "memory");                       \
        __builtin_amdgcn_sched_barrier(0);                                      \
        float a0_ = 0.f, a1_ = 0.f, a2_ = 0.f, a3_ = 0.f;                       \
        _Pragma("unroll")                                                       \
        for (int i_ = 0; i_ < 8; ++i_) {                                        \
            _Pragma("unroll")                                                   \
            for (int e_ = 0; e_ < 8; ++e_) {                                    \
                const int k_ = 8 * i_ + e_;                                     \
                const float hs_ = __int_as_float(                               \
                    __builtin_amdgcn_readlane(__float_as_int(vh_), k_));        \
                const float wf_ = (float)CUR.w[i_][e_];                         \
                if ((k_ & 3) == 0)      a0_ = fmaf(wf_, hs_, a0_);              \
                else if ((k_ & 3) == 1) a1_ = fmaf(wf_, hs_, a1_);              \
                else if ((k_ & 3) == 2) a2_ = fmaf(wf_, hs_, a2_);              \
                else                    a3_ = fmaf(wf_, hs_, a3_);              \
            }                                                                   \
        }                                                                       \
        float acc_ = fmaf(CUR.wb[0], xj_, CUR.wb[1]);                           \
        acc_ = fmaf(dec_, (a0_ + a1_) + (a2_ + a3_), acc_);                     \
        const float gi_ = quad_bcast<0>(acc_);                                  \
        const float gf_ = quad_bcast<1>(acc_);                                  \
        const float go_ = quad_bcast<2>(acc_);                                  \
        const float gc_ = quad_bcast<3>(acc_);                                  \
        asm volatile("s_waitcnt lgkmcnt(0)" ::: "memory");                      \
        __builtin_amdgcn_sched_barrier(0);                                      \
        __builtin_amdgcn_s_barrier();   /* B1: all h reads done */              \
        const float cn_ = fmaf(fsigm(gf_), cu, fsigm(gi_) * ftanh(gc_));        \
        cu = cn_;                                                               \
        if (q == 0) h_lds[(mj_ << 6) + u] = fsigm(go_) * ftanh(cn_);            \
        asm volatile("s_waitcnt lgkmcnt(0)" ::: "memory");                      \
        __builtin_amdgcn_sched_barrier(0);                                      \
        __builtin_amdgcn_s_barrier();   /* B2: h write visible */               \
    }

__global__ __launch_bounds__(256, 1)
void lstm_pre(const float* __restrict__ X, const int* __restrict__ lengths,
              const _Float16* __restrict__ Gw, const f32x2* __restrict__ Gwb,
              const float* __restrict__ wdec, const float* __restrict__ bdec,
              const float* __restrict__ Wo, const float* __restrict__ bo,
              float* __restrict__ out)
{
    __shared__ __align__(16) float h_lds[Fn * Hn];   // 32 KB
    __shared__ float c_lds[Hn];
    __shared__ int   m_lds[Ln];
    __shared__ float x_lds[Ln];
    __shared__ float d_lds[Ln];
    __shared__ float wd_lds[Fn], bd_lds[Fn];
    __shared__ float red_lds[4 * NCn];
    __shared__ float logit_lds[NCn];

    const int b   = blockIdx.x;
    const int tid = threadIdx.x;
    const int l   = tid & 63;
    const int w   = tid >> 6;
    const int q   = l & 3;             // 0=i,1=f,2=o,3=c
    const int u   = w * 16 + (l >> 2); // hidden unit owned by this quad

    const float* mrow = X + ((size_t)b * 4 + 1) * Ln;
    const float* xrow = X + ((size_t)b * 4 + 2) * Ln;
    const float* drow = X + ((size_t)b * 4 + 3) * Ln;

    for (int i = tid; i < Fn * Hn; i += 256) h_lds[i] = 0.0f;
    if (tid < Fn) { wd_lds[tid] = wdec[tid]; bd_lds[tid] = bdec[tid]; }
    for (int i = tid; i < Ln; i += 256) {
        m_lds[i] = (int)mrow[i];
        x_lds[i] = xrow[i];
        d_lds[i] = drow[i];
    }
    __syncthreads();

    int len = lengths[b];
    if (len > Ln) len = Ln;

    float cu = 0.0f;   // c[u], replicated across the quad

    if (len > 0) {
        SlabR s0, s1, s2;
        ISSUE_R(s0, m_lds[0]);
        { const int i1 = (1 < len) ? 1 : 0; ISSUE_R(s1, m_lds[i1]); }
        int j = 0;
        for (;;) {
            STEPR(j, s0, s2); if (++j >= len) break;
            STEPR(j, s1, s0); if (++j >= len) break;
            STEPR(j, s2, s1); if (++j >= len) break;
        }
        asm volatile("s_waitcnt vmcnt(0)" ::: "memory");
    }
    if (q == 0) c_lds[u] = cu;
    __syncthreads();

    // ---- output head: logits = W_out @ [c; h.flatten()] + b_out, softmax ----
    float p[NCn];
#pragma unroll
    for (int c = 0; c < NCn; ++c) p[c] = 0.0f;
    for (int i = tid; i < IN_DIM; i += 256) {
        const float fv = (i < Hn) ? c_lds[i] : h_lds[i - Hn];
#pragma unroll
        for (int c = 0; c < NCn; ++c)
            p[c] = fmaf(Wo[(size_t)c * IN_DIM + i], fv, p[c]);
    }
#pragma unroll
    for (int c = 0; c < NCn; ++c) {
        float v = p[c];
#pragma unroll
        for (int off = 32; off > 0; off >>= 1) v += __shfl_down(v, off, 64);
        if (l == 0) red_lds[w * NCn + c] = v;
    }
    __syncthreads();
    if (tid < NCn) {
        logit_lds[tid] = red_lds[tid] + red_lds[NCn + tid] +
                         red_lds[2 * NCn + tid] + red_lds[3 * NCn + tid] + bo[tid];
    }
    __syncthreads();
    if (tid == 0) {
        float mx = logit_lds[0];
        for (int c = 1; c < NCn; ++c) mx = fmaxf(mx, logit_lds[c]);
        float e[NCn], s = 0.0f;
        for (int c = 0; c < NCn; ++c) { e[c] = expf(logit_lds[c] - mx); s += e[c]; }
        const float inv = 1.0f / s;
        for (int c = 0; c < NCn; ++c) out[(size_t)b * NCn + c] = e[c] * inv;
    }
}

// ---- fallback (no workspace): raw f32 weights each step ----
__global__ __launch_bounds__(256)
void lstm_fallback(const float* __restrict__ X, const int* __restrict__ lengths,
                   const float* __restrict__ Wg, const float* __restrict__ bg,
                   const float* __restrict__ wdec, const float* __restrict__ bdec,
                   const float* __restrict__ Wo, const float* __restrict__ bo,
                   float* __restrict__ out)
{
    __shared__ __align__(16) float h_lds[Fn * Hn];
    __shared__ float c_lds[Hn];
    __shared__ int   m_lds[Ln];
    __shared__ float x_lds[Ln];
    __shared__ float d_lds[Ln];
    __shared__ float wd_lds[Fn], bd_lds[Fn];
    __shared__ float red_lds[4 * NCn];
    __shared__ float logit_lds[NCn];

    const int b   = blockIdx.x;
    const int tid = threadIdx.x;
    const int l   = tid & 63;
    const int w   = tid >> 6;
    const int q   = l & 3;
    const int u   = w * 16 + (l >> 2);

    const float* mrow = X + ((size_t)b * 4 + 1) * Ln;
    const float* xrow = X + ((size_t)b * 4 + 2) * Ln;
    const float* drow = X + ((size_t)b * 4 + 3) * Ln;

    for (int i = tid; i < Fn * Hn; i += 256) h_lds[i] = 0.0f;
    if (tid < Hn) c_lds[tid] = 0.0f;
    if (tid < Fn) { wd_lds[tid] = wdec[tid]; bd_lds[tid] = bdec[tid]; }
    for (int i = tid; i < Ln; i += 256) {
        m_lds[i] = (int)mrow[i];
        x_lds[i] = xrow[i];
        d_lds[i] = drow[i];
    }
    __syncthreads();

    int len = lengths[b];
    if (len > Ln) len = Ln;
    const int g_raw = q * 64 + u;

    for (int j = 0; j < len; ++j) {
        const int   mj = m_lds[j];
        const float xj = x_lds[j];
        const float dj = d_lds[j];
        const float dec = expf(-fmaxf(0.0f, fmaf(wd_lds[mj], dj, bd_lds[mj])));
        const float4* hp = (const float4*)(h_lds + mj * Hn);
        const float* row = Wg + ((size_t)mj * NGn + g_raw) * 65;
        float acc = fmaf(row[0], xj, bg[mj * NGn + g_raw]);
        float a0 = 0.f, a1 = 0.f, a2 = 0.f, a3 = 0.f;
#pragma unroll
        for (int k4 = 0; k4 < 16; ++k4) {
            float4 hv = hp[k4];
            a0 = fmaf(row[1 + 4*k4 + 0], hv.x, a0);
            a1 = fmaf(row[1 + 4*k4 + 1], hv.y, a1);
            a2 = fmaf(row[1 + 4*k4 + 2], hv.z, a2);
            a3 = fmaf(row[1 + 4*k4 + 3], hv.w, a3);
        }
        acc = fmaf(dec, (a0 + a1) + (a2 + a3), acc);
        const int base = l & ~3;
        const float gi = __shfl(acc, base + 0, 64);
        const float gf = __shfl(acc, base + 1, 64);
        const float go = __shfl(acc, base + 2, 64);
        const float gc = __shfl(acc, base + 3, 64);
        __syncthreads();
        const float c_new = fmaf(sigm_slow(gf), c_lds[u], sigm_slow(gi) * tanhf(gc));
        if (q == 0) {
            c_lds[u] = c_new;
            h_lds[mj * Hn + u] = sigm_slow(go) * tanhf(c_new);
        }
        __syncthreads();
    }

    float p[NCn];
#pragma unroll
    for (int c = 0; c < NCn; ++c) p[c] = 0.0f;
    for (int i = tid; i < IN_DIM; i += 256) {
        const float fv = (i < Hn) ? c_lds[i] : h_lds[i - Hn];
#pragma unroll
        for (int c = 0; c < NCn; ++c)
            p[c] = fmaf(Wo[(size_t)c * IN_DIM + i], fv, p[c]);
    }
#pragma unroll
    for (int c = 0; c < NCn; ++c) {
        float v = p[c];
#pragma unroll
        for (int off = 32; off > 0; off >>= 1) v += __shfl_down(v, off, 64);
        if (l == 0) red_lds[w * NCn + c] = v;
    }
    __syncthreads();
    if (tid < NCn) {
        logit_lds[tid] = red_lds[tid] + red_lds[NCn + tid] +
                         red_lds[2 * NCn + tid] + red_lds[3 * NCn + tid] + bo[tid];
    }
    __syncthreads();
    if (tid == 0) {
        float mx = logit_lds[0];
        for (int c = 1; c < NCn; ++c) mx = fmaxf(mx, logit_lds[c]);
        float e[NCn], s = 0.0f;
        for (int c = 0; c < NCn; ++c) { e[c] = expf(logit_lds[c] - mx); s += e[c]; }
        const float inv = 1.0f / s;
        for (int c = 0; c < NCn; ++c) out[(size_t)b * NCn + c] = e[c] * inv;
    }
}

extern "C" void kernel_launch(void* const* d_in, const int* in_sizes, int n_in,
                              void* d_out, int out_size, void* d_ws, size_t ws_size,
                              hipStream_t stream)
{
    const float* X      = (const float*)d_in[0];
    const int*   len    = (const int*)  d_in[1];
    const float* Wg     = (const float*)d_in[2];
    const float* bg     = (const float*)d_in[3];
    const float* wdec   = (const float*)d_in[4];
    const float* bdec   = (const float*)d_in[5];
    const float* Wo     = (const float*)d_in[6];
    const float* bo     = (const float*)d_in[7];
    float*       out    = (float*)d_out;

    const size_t gw_bytes  = (size_t)Fn * 8 * NGn * 8 * sizeof(_Float16); // 4,194,304
    const size_t gwb_bytes = (size_t)Fn * NGn * sizeof(f32x2);            // 262,144
    const size_t need      = gw_bytes + gwb_bytes;

    if (ws_size >= need) {
        _Float16* Gw  = (_Float16*)d_ws;
        f32x2*    Gwb = (f32x2*)((char*)d_ws + gw_bytes);
        prep_f16<<<Fn, 256, 0, stream>>>(Wg, bg, Gw, Gwb);
        lstm_pre<<<Bn, 256, 0, stream>>>(X, len, Gw, Gwb,
                                         wdec, bdec, Wo, bo, out);
    } else {
        lstm_fallback<<<Bn, 256, 0, stream>>>(X, len, Wg, bg,
                                              wdec, bdec, Wo, bo, out);
    }
}

// Round 6
// 653.311 us; speedup vs baseline: 1.4589x; 1.4589x over previous
//
#include <hip/hip_runtime.h>
#include <cstdint>
#include <cstddef>

#define Bn 128
#define Ln 1024
#define Fn 128
#define Hn 64
#define NGn 256           // 4*H
#define NCn 16
#define IN_DIM (Hn + Fn*Hn)   // 8256

typedef float    f32x4 __attribute__((ext_vector_type(4)));
typedef float    f32x2 __attribute__((ext_vector_type(2)));
typedef _Float16 f16x8 __attribute__((ext_vector_type(8)));

struct SlabR { f16x8 w[8]; f32x2 wb; };   // 32 + 2 VGPRs

__device__ __forceinline__ float fsigm(float x) {
    return __fdividef(1.0f, 1.0f + __expf(-x));
}
__device__ __forceinline__ float ftanh(float x) {
    float e = __expf(2.0f * x);
    return 1.0f - __fdividef(2.0f, e + 1.0f);
}
__device__ __forceinline__ float sigm_slow(float x) { return 1.0f / (1.0f + expf(-x)); }

template<int P>
__device__ __forceinline__ float qperm(float v) {
    return __int_as_float(__builtin_amdgcn_mov_dpp(__float_as_int(v), P, 0xf, 0xf, true));
}
// quad all-reduce (sum): after this every lane of the quad holds the quad sum
#define QRED(A) do { A += qperm<0xB1>(A); A += qperm<0x4E>(A); } while (0)

// thread tid: q = tid&3 (k-quarter AND bias-gate), u = (tid>>6)*16 + ((tid>>2)&15)
// lane handles gate rows r=0..3 (i,f,o,c) of unit u, k in [16q, 16q+16)
// Gw[((f*8 + c)*256 + tid)*8 + e] = (f16) W_gates[f][(c>>1)*64 + u][1 + 16q + 8*(c&1) + e]
// Gwb[f*256 + tid] = (W_gates[f][q*64+u][0], b_gates[f][q*64+u])
__global__ __launch_bounds__(256)
void prep_f16(const float* __restrict__ Wg, const float* __restrict__ bg,
              _Float16* __restrict__ Gw, f32x2* __restrict__ Gwb)
{
    const int f = blockIdx.x, tid = threadIdx.x;
    const int q = tid & 3;
    const int u = (tid >> 6) * 16 + ((tid >> 2) & 15);
    {
        const float* srcq = Wg + ((size_t)f * NGn + q * 64 + u) * 65;
        f32x2 wb; wb[0] = srcq[0]; wb[1] = bg[f * NGn + q * 64 + u];
        Gwb[f * NGn + tid] = wb;
    }
#pragma unroll
    for (int c = 0; c < 8; ++c) {
        const int r = c >> 1;
        const float* src = Wg + ((size_t)f * NGn + r * 64 + u) * 65;
        f16x8 v;
#pragma unroll
        for (int e = 0; e < 8; ++e) v[e] = (_Float16)src[1 + 16 * q + 8 * (c & 1) + e];
        *(f16x8*)(Gw + (((size_t)f * 8 + c) * NGn + tid) * 8) = v;
    }
}

// Issue one step's per-thread W chunk (9 pinned loads) into register slab SL.
#define ISSUE_R(SL, MN)                                                         \
    do {                                                                        \
        const uint32_t vo_ = ((uint32_t)(MN) << 15) + ((uint32_t)tid << 4);     \
        _Pragma("unroll")                                                       \
        for (int i_ = 0; i_ < 8; ++i_)                                          \
            asm volatile("global_load_dwordx4 %0, %1, %2"                       \
                         : "=v"(SL.w[i_])                                       \
                         : "v"(vo_ + (uint32_t)(i_ * 4096)), "s"(Gw));          \
        asm volatile("global_load_dwordx2 %0, %1, %2"                           \
                     : "=v"(SL.wb)                                              \
                     : "v"(((uint32_t)(MN) << 11) + ((uint32_t)tid << 3)),      \
                       "s"(Gwb));                                               \
    } while (0)

// One step consuming register slab CUR; issues step J+1's slab into FREE.
// vmcnt(9): FREE's 9 loads stay in flight, CUR's loads certified complete.
#define STEPR(CUR, FREE)                                                        \
    {                                                                           \
        const int hb_ = (mj << 6) + (q << 4);                                   \
        const f32x4 hv0 = *(const f32x4*)(h_lds + hb_ + 0);                     \
        const f32x4 hv1 = *(const f32x4*)(h_lds + hb_ + 4);                     \
        const f32x4 hv2 = *(const f32x4*)(h_lds + hb_ + 8);                     \
        const f32x4 hv3 = *(const f32x4*)(h_lds + hb_ + 12);                    \
        const int   jn_ = (j + 1 < len) ? j + 1 : j;                            \
        const int   mn_ = m_lds[jn_];                                           \
        const f32x2 xdn_ = xd_lds[jn_];                                         \
        asm volatile("s_waitcnt lgkmcnt(0)" ::: "memory");                      \
        __builtin_amdgcn_sched_barrier(0);                                      \
        __builtin_amdgcn_s_barrier();   /* B1: all h reads done */              \
        const f32x2 wbn_ = wdbd_lds[mn_];  /* prefetch next decay params */     \
        ISSUE_R(FREE, mn_);                                                     \
        const float dec_ = __expf(-fmaxf(0.0f, fmaf(wdj, dj, bdj)));            \
        asm volatile("s_waitcnt vmcnt(9)" ::: "memory");                        \
        __builtin_amdgcn_sched_barrier(0);                                      \
        float a0_ = 0.f, a1_ = 0.f, a2_ = 0.f, a3_ = 0.f;                       \
        _Pragma("unroll")                                                       \
        for (int e_ = 0; e_ < 8; ++e_) {                                        \
            const float he_ = (e_ < 4) ? hv0[e_ & 3] : hv1[e_ & 3];             \
            const float ho_ = (e_ < 4) ? hv2[e_ & 3] : hv3[e_ & 3];             \
            a0_ = fmaf((float)CUR.w[0][e_], he_, a0_);                          \
            a0_ = fmaf((float)CUR.w[1][e_], ho_, a0_);                          \
            a1_ = fmaf((float)CUR.w[2][e_], he_, a1_);                          \
            a1_ = fmaf((float)CUR.w[3][e_], ho_, a1_);                          \
            a2_ = fmaf((float)CUR.w[4][e_], he_, a2_);                          \
            a2_ = fmaf((float)CUR.w[5][e_], ho_, a2_);                          \
            a3_ = fmaf((float)CUR.w[6][e_], he_, a3_);                          \
            a3_ = fmaf((float)CUR.w[7][e_], ho_, a3_);                          \
        }                                                                       \
        const float own_ = fmaf(CUR.wb[0], xj, CUR.wb[1]);                      \
        a0_ = fmaf(a0_, dec_, (q == 0) ? own_ : 0.0f);                          \
        a1_ = fmaf(a1_, dec_, (q == 1) ? own_ : 0.0f);                          \
        a2_ = fmaf(a2_, dec_, (q == 2) ? own_ : 0.0f);                          \
        a3_ = fmaf(a3_, dec_, (q == 3) ? own_ : 0.0f);                          \
        QRED(a0_); QRED(a1_); QRED(a2_); QRED(a3_);                             \
        const float cn_ = fmaf(fsigm(a1_), cu, fsigm(a0_) * ftanh(a3_));        \
        cu = cn_;                                                               \
        if (q == 0) h_lds[(mj << 6) + u] = fsigm(a2_) * ftanh(cn_);             \
        asm volatile("s_waitcnt lgkmcnt(0)" ::: "memory");                      \
        __builtin_amdgcn_sched_barrier(0);                                      \
        __builtin_amdgcn_s_barrier();   /* B2: h write visible */               \
        mj = mn_; xj = xdn_[0]; dj = xdn_[1]; wdj = wbn_[0]; bdj = wbn_[1];     \
    }

__global__ __launch_bounds__(256, 1)
void lstm_pre(const float* __restrict__ X, const int* __restrict__ lengths,
              const _Float16* __restrict__ Gw, const f32x2* __restrict__ Gwb,
              const float* __restrict__ wdec, const float* __restrict__ bdec,
              const float* __restrict__ Wo, const float* __restrict__ bo,
              float* __restrict__ out)
{
    __shared__ __align__(16) float h_lds[Fn * Hn];   // 32 KB
    __shared__ float c_lds[Hn];
    __shared__ int   m_lds[Ln];
    __shared__ __align__(8) f32x2 xd_lds[Ln];        // (x, delta)
    __shared__ __align__(8) f32x2 wdbd_lds[Fn];      // (w_decay, b_decay)
    __shared__ float red_lds[4 * NCn];
    __shared__ float logit_lds[NCn];

    const int b   = blockIdx.x;
    const int tid = threadIdx.x;
    const int l   = tid & 63;
    const int w   = tid >> 6;
    const int q   = l & 3;             // k-quarter AND bias gate
    const int u   = w * 16 + (l >> 2); // hidden unit owned by this quad

    const float* mrow = X + ((size_t)b * 4 + 1) * Ln;
    const float* xrow = X + ((size_t)b * 4 + 2) * Ln;
    const float* drow = X + ((size_t)b * 4 + 3) * Ln;

    for (int i = tid; i < Fn * Hn; i += 256) h_lds[i] = 0.0f;
    if (tid < Fn) { f32x2 t; t[0] = wdec[tid]; t[1] = bdec[tid]; wdbd_lds[tid] = t; }
    for (int i = tid; i < Ln; i += 256) {
        m_lds[i] = (int)mrow[i];
        f32x2 t; t[0] = xrow[i]; t[1] = drow[i];
        xd_lds[i] = t;
    }
    __syncthreads();

    int len = lengths[b];
    if (len > Ln) len = Ln;

    float cu = 0.0f;   // c[u], replicated across the quad

    if (len > 0) {
        // prologue: step-0 params + slab
        int   mj = m_lds[0];
        f32x2 xd0 = xd_lds[0];
        float xj = xd0[0], dj = xd0[1];
        f32x2 wb0 = wdbd_lds[mj];
        float wdj = wb0[0], bdj = wb0[1];

        SlabR sA, sB;
        ISSUE_R(sA, mj);

        int j = 0;
        for (;;) {
            STEPR(sA, sB); if (++j >= len) break;
            STEPR(sB, sA); if (++j >= len) break;
        }
        asm volatile("s_waitcnt vmcnt(0)" ::: "memory");
    }
    if (q == 0) c_lds[u] = cu;
    __syncthreads();

    // ---- output head: logits = W_out @ [c; h.flatten()] + b_out, softmax ----
    float p[NCn];
#pragma unroll
    for (int c = 0; c < NCn; ++c) p[c] = 0.0f;
    for (int i = tid; i < IN_DIM; i += 256) {
        const float fv = (i < Hn) ? c_lds[i] : h_lds[i - Hn];
#pragma unroll
        for (int c = 0; c < NCn; ++c)
            p[c] = fmaf(Wo[(size_t)c * IN_DIM + i], fv, p[c]);
    }
#pragma unroll
    for (int c = 0; c < NCn; ++c) {
        float v = p[c];
#pragma unroll
        for (int off = 32; off > 0; off >>= 1) v += __shfl_down(v, off, 64);
        if (l == 0) red_lds[w * NCn + c] = v;
    }
    __syncthreads();
    if (tid < NCn) {
        logit_lds[tid] = red_lds[tid] + red_lds[NCn + tid] +
                         red_lds[2 * NCn + tid] + red_lds[3 * NCn + tid] + bo[tid];
    }
    __syncthreads();
    if (tid == 0) {
        float mx = logit_lds[0];
        for (int c = 1; c < NCn; ++c) mx = fmaxf(mx, logit_lds[c]);
        float e[NCn], s = 0.0f;
        for (int c = 0; c < NCn; ++c) { e[c] = expf(logit_lds[c] - mx); s += e[c]; }
        const float inv = 1.0f / s;
        for (int c = 0; c < NCn; ++c) out[(size_t)b * NCn + c] = e[c] * inv;
    }
}

// ---- fallback (no workspace): raw f32 weights each step ----
__global__ __launch_bounds__(256)
void lstm_fallback(const float* __restrict__ X, const int* __restrict__ lengths,
                   const float* __restrict__ Wg, const float* __restrict__ bg,
                   const float* __restrict__ wdec, const float* __restrict__ bdec,
                   const float* __restrict__ Wo, const float* __restrict__ bo,
                   float* __restrict__ out)
{
    __shared__ __align__(16) float h_lds[Fn * Hn];
    __shared__ float c_lds[Hn];
    __shared__ int   m_lds[Ln];
    __shared__ float x_lds[Ln];
    __shared__ float d_lds[Ln];
    __shared__ float wd_lds[Fn], bd_lds[Fn];
    __shared__ float red_lds[4 * NCn];
    __shared__ float logit_lds[NCn];

    const int b   = blockIdx.x;
    const int tid = threadIdx.x;
    const int l   = tid & 63;
    const int w   = tid >> 6;
    const int q   = l & 3;
    const int u   = w * 16 + (l >> 2);

    const float* mrow = X + ((size_t)b * 4 + 1) * Ln;
    const float* xrow = X + ((size_t)b * 4 + 2) * Ln;
    const float* drow = X + ((size_t)b * 4 + 3) * Ln;

    for (int i = tid; i < Fn * Hn; i += 256) h_lds[i] = 0.0f;
    if (tid < Hn) c_lds[tid] = 0.0f;
    if (tid < Fn) { wd_lds[tid] = wdec[tid]; bd_lds[tid] = bdec[tid]; }
    for (int i = tid; i < Ln; i += 256) {
        m_lds[i] = (int)mrow[i];
        x_lds[i] = xrow[i];
        d_lds[i] = drow[i];
    }
    __syncthreads();

    int len = lengths[b];
    if (len > Ln) len = Ln;
    const int g_raw = q * 64 + u;

    for (int j = 0; j < len; ++j) {
        const int   mj = m_lds[j];
        const float xj = x_lds[j];
        const float dj = d_lds[j];
        const float dec = expf(-fmaxf(0.0f, fmaf(wd_lds[mj], dj, bd_lds[mj])));
        const float4* hp = (const float4*)(h_lds + mj * Hn);
        const float* row = Wg + ((size_t)mj * NGn + g_raw) * 65;
        float acc = fmaf(row[0], xj, bg[mj * NGn + g_raw]);
        float a0 = 0.f, a1 = 0.f, a2 = 0.f, a3 = 0.f;
#pragma unroll
        for (int k4 = 0; k4 < 16; ++k4) {
            float4 hv = hp[k4];
            a0 = fmaf(row[1 + 4*k4 + 0], hv.x, a0);
            a1 = fmaf(row[1 + 4*k4 + 1], hv.y, a1);
            a2 = fmaf(row[1 + 4*k4 + 2], hv.z, a2);
            a3 = fmaf(row[1 + 4*k4 + 3], hv.w, a3);
        }
        acc = fmaf(dec, (a0 + a1) + (a2 + a3), acc);
        const int base = l & ~3;
        const float gi = __shfl(acc, base + 0, 64);
        const float gf = __shfl(acc, base + 1, 64);
        const float go = __shfl(acc, base + 2, 64);
        const float gc = __shfl(acc, base + 3, 64);
        __syncthreads();
        const float c_new = fmaf(sigm_slow(gf), c_lds[u], sigm_slow(gi) * tanhf(gc));
        if (q == 0) {
            c_lds[u] = c_new;
            h_lds[mj * Hn + u] = sigm_slow(go) * tanhf(c_new);
        }
        __syncthreads();
    }

    float p[NCn];
#pragma unroll
    for (int c = 0; c < NCn; ++c) p[c] = 0.0f;
    for (int i = tid; i < IN_DIM; i += 256) {
        const float fv = (i < Hn) ? c_lds[i] : h_lds[i - Hn];
#pragma unroll
        for (int c = 0; c < NCn; ++c)
            p[c] = fmaf(Wo[(size_t)c * IN_DIM + i], fv, p[c]);
    }
#pragma unroll
    for (int c = 0; c < NCn; ++c) {
        float v = p[c];
#pragma unroll
        for (int off = 32; off > 0; off >>= 1) v += __shfl_down(v, off, 64);
        if (l == 0) red_lds[w * NCn + c] = v;
    }
    __syncthreads();
    if (tid < NCn) {
        logit_lds[tid] = red_lds[tid] + red_lds[NCn + tid] +
                         red_lds[2 * NCn + tid] + red_lds[3 * NCn + tid] + bo[tid];
    }
    __syncthreads();
    if (tid == 0) {
        float mx = logit_lds[0];
        for (int c = 1; c < NCn; ++c) mx = fmaxf(mx, logit_lds[c]);
        float e[NCn], s = 0.0f;
        for (int c = 0; c < NCn; ++c) { e[c] = expf(logit_lds[c] - mx); s += e[c]; }
        const float inv = 1.0f / s;
        for (int c = 0; c < NCn; ++c) out[(size_t)b * NCn + c] = e[c] * inv;
    }
}

extern "C" void kernel_launch(void* const* d_in, const int* in_sizes, int n_in,
                              void* d_out, int out_size, void* d_ws, size_t ws_size,
                              hipStream_t stream)
{
    const float* X      = (const float*)d_in[0];
    const int*   len    = (const int*)  d_in[1];
    const float* Wg     = (const float*)d_in[2];
    const float* bg     = (const float*)d_in[3];
    const float* wdec   = (const float*)d_in[4];
    const float* bdec   = (const float*)d_in[5];
    const float* Wo     = (const float*)d_in[6];
    const float* bo     = (const float*)d_in[7];
    float*       out    = (float*)d_out;

    const size_t gw_bytes  = (size_t)Fn * 8 * NGn * 8 * sizeof(_Float16); // 4,194,304
    const size_t gwb_bytes = (size_t)Fn * NGn * sizeof(f32x2);            // 262,144
    const size_t need      = gw_bytes + gwb_bytes;

    if (ws_size >= need) {
        _Float16* Gw  = (_Float16*)d_ws;
        f32x2*    Gwb = (f32x2*)((char*)d_ws + gw_bytes);
        prep_f16<<<Fn, 256, 0, stream>>>(Wg, bg, Gw, Gwb);
        lstm_pre<<<Bn, 256, 0, stream>>>(X, len, Gw, Gwb,
                                         wdec, bdec, Wo, bo, out);
    } else {
        lstm_fallback<<<Bn, 256, 0, stream>>>(X, len, Wg, bg,
                                              wdec, bdec, Wo, bo, out);
    }
}

// Round 7
// 619.700 us; speedup vs baseline: 1.5380x; 1.0542x over previous
//
#include <hip/hip_runtime.h>
#include <cstdint>
#include <cstddef>

#define Bn 128
#define Ln 1024
#define Fn 128
#define Hn 64
#define NGn 256           // 4*H
#define NCn 16
#define IN_DIM (Hn + Fn*Hn)   // 8256

typedef float    f32x4 __attribute__((ext_vector_type(4)));
typedef float    f32x2 __attribute__((ext_vector_type(2)));
typedef _Float16 f16x8 __attribute__((ext_vector_type(8)));
typedef _Float16 f16x2 __attribute__((ext_vector_type(2)));

struct SlabR { f16x8 w[8]; f32x2 wb; };   // 32 + 2 VGPRs
union U8 { f16x8 v; f16x2 p[4]; };

__device__ __forceinline__ float fsigm(float x) {
    return __fdividef(1.0f, 1.0f + __expf(-x));
}
__device__ __forceinline__ float ftanh(float x) {
    float e = __expf(2.0f * x);
    return 1.0f - __fdividef(2.0f, e + 1.0f);
}
__device__ __forceinline__ float sigm_slow(float x) { return 1.0f / (1.0f + expf(-x)); }

template<int P>
__device__ __forceinline__ float qperm(float v) {
    return __int_as_float(__builtin_amdgcn_mov_dpp(__float_as_int(v), P, 0xf, 0xf, true));
}
// quad all-reduce (sum): after this every lane of the quad holds the quad sum
#define QRED(A) do { A += qperm<0xB1>(A); A += qperm<0x4E>(A); } while (0)

#if __has_builtin(__builtin_amdgcn_fdot2)
#define DOT2(WP, HP, ACC) __builtin_amdgcn_fdot2((WP), (HP), (ACC), false)
#else
#define DOT2(WP, HP, ACC) fmaf((float)(WP)[0], (float)(HP)[0], \
                               fmaf((float)(WP)[1], (float)(HP)[1], (ACC)))
#endif

// thread tid: q = tid&3 (k-quarter AND bias-gate), u = (tid>>6)*16 + ((tid>>2)&15)
// Gw[((f*8 + c)*256 + tid)*8 + e] = (f16) W_gates[f][(c>>1)*64 + u][1 + 16q + 8*(c&1) + e]
// (consecutive k inside each f16x8 -> natural (k,k+1) pairs for v_dot2)
// Gwb[f*256 + tid] = (W_gates[f][q*64+u][0], b_gates[f][q*64+u])
__global__ __launch_bounds__(256)
void prep_f16(const float* __restrict__ Wg, const float* __restrict__ bg,
              _Float16* __restrict__ Gw, f32x2* __restrict__ Gwb)
{
    const int f = blockIdx.x, tid = threadIdx.x;
    const int q = tid & 3;
    const int u = (tid >> 6) * 16 + ((tid >> 2) & 15);
    {
        const float* srcq = Wg + ((size_t)f * NGn + q * 64 + u) * 65;
        f32x2 wb; wb[0] = srcq[0]; wb[1] = bg[f * NGn + q * 64 + u];
        Gwb[f * NGn + tid] = wb;
    }
#pragma unroll
    for (int c = 0; c < 8; ++c) {
        const int r = c >> 1;
        const float* src = Wg + ((size_t)f * NGn + r * 64 + u) * 65;
        f16x8 v;
#pragma unroll
        for (int e = 0; e < 8; ++e) v[e] = (_Float16)src[1 + 16 * q + 8 * (c & 1) + e];
        *(f16x8*)(Gw + (((size_t)f * 8 + c) * NGn + tid) * 8) = v;
    }
}

// Issue one step's per-thread W chunk (9 pinned loads) into register slab SL.
#define ISSUE_R(SL, MN)                                                         \
    do {                                                                        \
        const uint32_t vo_ = ((uint32_t)(MN) << 15) + ((uint32_t)tid << 4);     \
        _Pragma("unroll")                                                       \
        for (int i_ = 0; i_ < 8; ++i_)                                          \
            asm volatile("global_load_dwordx4 %0, %1, %2"                       \
                         : "=v"(SL.w[i_])                                       \
                         : "v"(vo_ + (uint32_t)(i_ * 4096)), "s"(Gw));          \
        asm volatile("global_load_dwordx2 %0, %1, %2"                           \
                     : "=v"(SL.wb)                                              \
                     : "v"(((uint32_t)(MN) << 11) + ((uint32_t)tid << 3)),      \
                       "s"(Gwb));                                               \
    } while (0)

// One step consuming register slab CUR; issues step J+1's slab into FREE.
// All long-latency ops issue at the top; barriers sit at the tail.
#define STEPD(CUR, FREE)                                                        \
    {                                                                           \
        ISSUE_R(FREE, m1);                                                      \
        const int jpf_ = (j + 2 < len) ? j + 2 : len - 1;                       \
        const f32x4 pn_ = pk[jpf_];   /* broadcast b128, consumed at tail */    \
        asm volatile("s_waitcnt vmcnt(9)" ::: "memory");  /* CUR certified */   \
        __builtin_amdgcn_sched_barrier(0);                                      \
        float a0_ = 0.f, a1_ = 0.f, a2_ = 0.f, a3_ = 0.f;                       \
        {                                                                       \
            U8 wa_, wb2_;                                                       \
            wa_.v = CUR.w[0]; wb2_.v = CUR.w[1];                                \
            _Pragma("unroll")                                                   \
            for (int e_ = 0; e_ < 4; ++e_) { a0_ = DOT2(wa_.p[e_], hA.p[e_], a0_); a0_ = DOT2(wb2_.p[e_], hB.p[e_], a0_); } \
            wa_.v = CUR.w[2]; wb2_.v = CUR.w[3];                                \
            _Pragma("unroll")                                                   \
            for (int e_ = 0; e_ < 4; ++e_) { a1_ = DOT2(wa_.p[e_], hA.p[e_], a1_); a1_ = DOT2(wb2_.p[e_], hB.p[e_], a1_); } \
            wa_.v = CUR.w[4]; wb2_.v = CUR.w[5];                                \
            _Pragma("unroll")                                                   \
            for (int e_ = 0; e_ < 4; ++e_) { a2_ = DOT2(wa_.p[e_], hA.p[e_], a2_); a2_ = DOT2(wb2_.p[e_], hB.p[e_], a2_); } \
            wa_.v = CUR.w[6]; wb2_.v = CUR.w[7];                                \
            _Pragma("unroll")                                                   \
            for (int e_ = 0; e_ < 4; ++e_) { a3_ = DOT2(wa_.p[e_], hA.p[e_], a3_); a3_ = DOT2(wb2_.p[e_], hB.p[e_], a3_); } \
        }                                                                       \
        const float own_ = fmaf(CUR.wb[0], xj, CUR.wb[1]);                      \
        a0_ = fmaf(a0_, dj, (q == 0) ? own_ : 0.0f);                            \
        a1_ = fmaf(a1_, dj, (q == 1) ? own_ : 0.0f);                            \
        a2_ = fmaf(a2_, dj, (q == 2) ? own_ : 0.0f);                            \
        a3_ = fmaf(a3_, dj, (q == 3) ? own_ : 0.0f);                            \
        QRED(a0_); QRED(a1_); QRED(a2_); QRED(a3_);                             \
        const float cn_ = fmaf(fsigm(a1_), cu, fsigm(a0_) * ftanh(a3_));        \
        cu = cn_;                                                               \
        const float hv_ = fsigm(a2_) * ftanh(cn_);                              \
        const float hp_ = __int_as_float(__builtin_amdgcn_ds_swizzle(           \
                              __float_as_int(hv_), 0x101F)); /* lane^4 */       \
        const int mwr_ = mj;                                                    \
        xj = x1; dj = d1; mj = m1;                                              \
        x1 = pn_[0]; d1 = pn_[1]; m1 = __float_as_int(pn_[2]);                  \
        asm volatile("s_waitcnt lgkmcnt(0)" ::: "memory");                      \
        __builtin_amdgcn_sched_barrier(0);                                      \
        __builtin_amdgcn_s_barrier();   /* B1: all reads/compute done */        \
        if ((l & 7) == 0) {                                                     \
            f16x2 pr_; pr_[0] = (_Float16)hv_; pr_[1] = (_Float16)hp_;          \
            *(f16x2*)(h16 + (mwr_ << 6) + u) = pr_;                             \
        }                                                                       \
        asm volatile("s_waitcnt lgkmcnt(0)" ::: "memory");                      \
        __builtin_amdgcn_sched_barrier(0);                                      \
        __builtin_amdgcn_s_barrier();   /* B2: h write visible */               \
        {   /* issue next step's h-row reads NOW; latency hides in next top */  \
            const f16x8* hp2_ = (const f16x8*)(h16 + (mj << 6) + (q << 4));     \
            hA.v = hp2_[0]; hB.v = hp2_[1];                                     \
        }                                                                       \
    }

__global__ __launch_bounds__(256, 1)
void lstm_pre(const float* __restrict__ X, const int* __restrict__ lengths,
              const _Float16* __restrict__ Gw, const f32x2* __restrict__ Gwb,
              const float* __restrict__ wdec, const float* __restrict__ bdec,
              const float* __restrict__ Wo, const float* __restrict__ bo,
              float* __restrict__ out)
{
    __shared__ __align__(16) _Float16 h16[Fn * Hn];   // 16 KB f16 h state
    __shared__ __align__(16) f32x4 pk[Ln];            // 16 KB {x, dec, m_bits, 0}
    __shared__ float c_lds[Hn];
    __shared__ float wd_s[Fn], bd_s[Fn];
    __shared__ float red_lds[4 * NCn];
    __shared__ float logit_lds[NCn];

    const int b   = blockIdx.x;
    const int tid = threadIdx.x;
    const int l   = tid & 63;
    const int w   = tid >> 6;
    const int q   = l & 3;             // k-quarter AND bias gate
    const int u   = w * 16 + (l >> 2); // hidden unit owned by this quad

    const float* mrow = X + ((size_t)b * 4 + 1) * Ln;
    const float* xrow = X + ((size_t)b * 4 + 2) * Ln;
    const float* drow = X + ((size_t)b * 4 + 3) * Ln;

    {
        f16x8 hz;
#pragma unroll
        for (int e = 0; e < 8; ++e) hz[e] = (_Float16)0.0f;
        for (int i = tid; i < (Fn * Hn / 8); i += 256) ((f16x8*)h16)[i] = hz;
    }
    if (tid < Fn) { wd_s[tid] = wdec[tid]; bd_s[tid] = bdec[tid]; }
    __syncthreads();

    // precompute packed per-step params: {x, dec, m} (one b128/step in loop)
    for (int jj = tid; jj < Ln; jj += 256) {
        const int   m  = (int)mrow[jj];
        const float xv = xrow[jj];
        const float dl = drow[jj];
        const float dec = __expf(-fmaxf(0.0f, fmaf(wd_s[m], dl, bd_s[m])));
        f32x4 t; t[0] = xv; t[1] = dec; t[2] = __int_as_float(m); t[3] = 0.0f;
        pk[jj] = t;
    }
    __syncthreads();

    int len = lengths[b];
    if (len > Ln) len = Ln;

    float cu = 0.0f;   // c[u], replicated across the quad

    if (len > 0) {
        f32x4 p0 = pk[0];
        f32x4 p1 = pk[(1 < len) ? 1 : 0];
        float xj = p0[0], dj = p0[1]; int mj = __float_as_int(p0[2]);
        float x1 = p1[0], d1 = p1[1]; int m1 = __float_as_int(p1[2]);

        SlabR sA, sB;
        ISSUE_R(sA, mj);

        U8 hA, hB;
        {
            const f16x8* hp = (const f16x8*)(h16 + (mj << 6) + (q << 4));
            hA.v = hp[0]; hB.v = hp[1];
        }

        int j = 0;
        for (;;) {
            STEPD(sA, sB); if (++j >= len) break;
            STEPD(sB, sA); if (++j >= len) break;
        }
        asm volatile("s_waitcnt vmcnt(0)" ::: "memory");
    }
    if (q == 0) c_lds[u] = cu;
    __syncthreads();

    // ---- output head: logits = W_out @ [c; h.flatten()] + b_out, softmax ----
    float p[NCn];
#pragma unroll
    for (int c = 0; c < NCn; ++c) p[c] = 0.0f;
    for (int i = tid; i < IN_DIM; i += 256) {
        const float fv = (i < Hn) ? c_lds[i] : (float)h16[i - Hn];
#pragma unroll
        for (int c = 0; c < NCn; ++c)
            p[c] = fmaf(Wo[(size_t)c * IN_DIM + i], fv, p[c]);
    }
#pragma unroll
    for (int c = 0; c < NCn; ++c) {
        float v = p[c];
#pragma unroll
        for (int off = 32; off > 0; off >>= 1) v += __shfl_down(v, off, 64);
        if (l == 0) red_lds[w * NCn + c] = v;
    }
    __syncthreads();
    if (tid < NCn) {
        logit_lds[tid] = red_lds[tid] + red_lds[NCn + tid] +
                         red_lds[2 * NCn + tid] + red_lds[3 * NCn + tid] + bo[tid];
    }
    __syncthreads();
    if (tid == 0) {
        float mx = logit_lds[0];
        for (int c = 1; c < NCn; ++c) mx = fmaxf(mx, logit_lds[c]);
        float e[NCn], s = 0.0f;
        for (int c = 0; c < NCn; ++c) { e[c] = expf(logit_lds[c] - mx); s += e[c]; }
        const float inv = 1.0f / s;
        for (int c = 0; c < NCn; ++c) out[(size_t)b * NCn + c] = e[c] * inv;
    }
}

// ---- fallback (no workspace): raw f32 weights each step ----
__global__ __launch_bounds__(256)
void lstm_fallback(const float* __restrict__ X, const int* __restrict__ lengths,
                   const float* __restrict__ Wg, const float* __restrict__ bg,
                   const float* __restrict__ wdec, const float* __restrict__ bdec,
                   const float* __restrict__ Wo, const float* __restrict__ bo,
                   float* __restrict__ out)
{
    __shared__ __align__(16) float h_lds[Fn * Hn];
    __shared__ float c_lds[Hn];
    __shared__ int   m_lds[Ln];
    __shared__ float x_lds[Ln];
    __shared__ float d_lds[Ln];
    __shared__ float wd_lds[Fn], bd_lds[Fn];
    __shared__ float red_lds[4 * NCn];
    __shared__ float logit_lds[NCn];

    const int b   = blockIdx.x;
    const int tid = threadIdx.x;
    const int l   = tid & 63;
    const int w   = tid >> 6;
    const int q   = l & 3;
    const int u   = w * 16 + (l >> 2);

    const float* mrow = X + ((size_t)b * 4 + 1) * Ln;
    const float* xrow = X + ((size_t)b * 4 + 2) * Ln;
    const float* drow = X + ((size_t)b * 4 + 3) * Ln;

    for (int i = tid; i < Fn * Hn; i += 256) h_lds[i] = 0.0f;
    if (tid < Hn) c_lds[tid] = 0.0f;
    if (tid < Fn) { wd_lds[tid] = wdec[tid]; bd_lds[tid] = bdec[tid]; }
    for (int i = tid; i < Ln; i += 256) {
        m_lds[i] = (int)mrow[i];
        x_lds[i] = xrow[i];
        d_lds[i] = drow[i];
    }
    __syncthreads();

    int len = lengths[b];
    if (len > Ln) len = Ln;
    const int g_raw = q * 64 + u;

    for (int j = 0; j < len; ++j) {
        const int   mj = m_lds[j];
        const float xj = x_lds[j];
        const float dj = d_lds[j];
        const float dec = expf(-fmaxf(0.0f, fmaf(wd_lds[mj], dj, bd_lds[mj])));
        const float4* hp = (const float4*)(h_lds + mj * Hn);
        const float* row = Wg + ((size_t)mj * NGn + g_raw) * 65;
        float acc = fmaf(row[0], xj, bg[mj * NGn + g_raw]);
        float a0 = 0.f, a1 = 0.f, a2 = 0.f, a3 = 0.f;
#pragma unroll
        for (int k4 = 0; k4 < 16; ++k4) {
            float4 hv = hp[k4];
            a0 = fmaf(row[1 + 4*k4 + 0], hv.x, a0);
            a1 = fmaf(row[1 + 4*k4 + 1], hv.y, a1);
            a2 = fmaf(row[1 + 4*k4 + 2], hv.z, a2);
            a3 = fmaf(row[1 + 4*k4 + 3], hv.w, a3);
        }
        acc = fmaf(dec, (a0 + a1) + (a2 + a3), acc);
        const int base = l & ~3;
        const float gi = __shfl(acc, base + 0, 64);
        const float gf = __shfl(acc, base + 1, 64);
        const float go = __shfl(acc, base + 2, 64);
        const float gc = __shfl(acc, base + 3, 64);
        __syncthreads();
        const float c_new = fmaf(sigm_slow(gf), c_lds[u], sigm_slow(gi) * tanhf(gc));
        if (q == 0) {
            c_lds[u] = c_new;
            h_lds[mj * Hn + u] = sigm_slow(go) * tanhf(c_new);
        }
        __syncthreads();
    }

    float p[NCn];
#pragma unroll
    for (int c = 0; c < NCn; ++c) p[c] = 0.0f;
    for (int i = tid; i < IN_DIM; i += 256) {
        const float fv = (i < Hn) ? c_lds[i] : h_lds[i - Hn];
#pragma unroll
        for (int c = 0; c < NCn; ++c)
            p[c] = fmaf(Wo[(size_t)c * IN_DIM + i], fv, p[c]);
    }
#pragma unroll
    for (int c = 0; c < NCn; ++c) {
        float v = p[c];
#pragma unroll
        for (int off = 32; off > 0; off >>= 1) v += __shfl_down(v, off, 64);
        if (l == 0) red_lds[w * NCn + c] = v;
    }
    __syncthreads();
    if (tid < NCn) {
        logit_lds[tid] = red_lds[tid] + red_lds[NCn + tid] +
                         red_lds[2 * NCn + tid] + red_lds[3 * NCn + tid] + bo[tid];
    }
    __syncthreads();
    if (tid == 0) {
        float mx = logit_lds[0];
        for (int c = 1; c < NCn; ++c) mx = fmaxf(mx, logit_lds[c]);
        float e[NCn], s = 0.0f;
        for (int c = 0; c < NCn; ++c) { e[c] = expf(logit_lds[c] - mx); s += e[c]; }
        const float inv = 1.0f / s;
        for (int c = 0; c < NCn; ++c) out[(size_t)b * NCn + c] = e[c] * inv;
    }
}

extern "C" void kernel_launch(void* const* d_in, const int* in_sizes, int n_in,
                              void* d_out, int out_size, void* d_ws, size_t ws_size,
                              hipStream_t stream)
{
    const float* X      = (const float*)d_in[0];
    const int*   len    = (const int*)  d_in[1];
    const float* Wg     = (const float*)d_in[2];
    const float* bg     = (const float*)d_in[3];
    const float* wdec   = (const float*)d_in[4];
    const float* bdec   = (const float*)d_in[5];
    const float* Wo     = (const float*)d_in[6];
    const float* bo     = (const float*)d_in[7];
    float*       out    = (float*)d_out;

    const size_t gw_bytes  = (size_t)Fn * 8 * NGn * 8 * sizeof(_Float16); // 4,194,304
    const size_t gwb_bytes = (size_t)Fn * NGn * sizeof(f32x2);            // 262,144
    const size_t need      = gw_bytes + gwb_bytes;

    if (ws_size >= need) {
        _Float16* Gw  = (_Float16*)d_ws;
        f32x2*    Gwb = (f32x2*)((char*)d_ws + gw_bytes);
        prep_f16<<<Fn, 256, 0, stream>>>(Wg, bg, Gw, Gwb);
        lstm_pre<<<Bn, 256, 0, stream>>>(X, len, Gw, Gwb,
                                         wdec, bdec, Wo, bo, out);
    } else {
        lstm_fallback<<<Bn, 256, 0, stream>>>(X, len, Wg, bg,
                                              wdec, bdec, Wo, bo, out);
    }
}